// Round 4
// baseline (96.737 us; speedup 1.0000x reference)
//
#include <hip/hip_runtime.h>

#define BATCH 4
#define SEQ   512
#define DIM   128
#define PADJ  516   // 512 + 4 f16 (8 B) row pad: row stride 1032 B breaks pow-2 banking

typedef _Float16 half8 __attribute__((ext_vector_type(8)));
typedef _Float16 half4 __attribute__((ext_vector_type(4)));
typedef float    f32x4 __attribute__((ext_vector_type(4)));

// load 8 consecutive f32, convert to half8 in registers
__device__ __forceinline__ half8 ld8h(const float* __restrict__ p) {
    const float4 a = *(const float4*)p;
    const float4 b = *(const float4*)(p + 4);
    half8 h;
    h[0] = (_Float16)a.x; h[1] = (_Float16)a.y; h[2] = (_Float16)a.z; h[3] = (_Float16)a.w;
    h[4] = (_Float16)b.x; h[5] = (_Float16)b.y; h[6] = (_Float16)b.z; h[7] = (_Float16)b.w;
    return h;
}

// ---------------------------------------------------------------------------
// Fully fused AFT: one launch, no workspace, no grid barrier.
// Block = (b, d-slice of 16, t-slice of 32); grid = 4 x 8 x 16 = 512 blocks.
// Phase 1 (into LDS):
//   ep_s [t][j]        = exp(pos[t0g+t][j])                 (32 x 512 f16)
//   ekk_s[2c+0][j]     = exp(k[b][j][d0g+c])                (den A-operand)
//   ekk_s[2c+1][j]     = ek * v[b][j][d0g+c]                (num A-operand)
//   q_s  [t][c]        = sigmoid(q-proj)                    (32 x 16 f32)
//   k/v proj: per-wave 128-token strip, MFMA 16x16x32 f16, W cols d0g..+16.
//   (each block redoes its 16-col projection over all 512 tokens: removes the
//    inter-kernel dependency entirely; x stays L2-hot, +2 GFLOP total chip-wide)
// Phase 2: D[m][t] = sum_j ekk_s[m][j] * ep_s[t][j], wave tile 16m x 16t,
//   4 waves = 32m x 32t, K=512 in 16 steps (2 interleaved acc chains).
// Epilogue: out = q * num / den  (lane regs hold den/num for d, d+1).
// ---------------------------------------------------------------------------
__global__ __launch_bounds__(256, 2) void k_fused(
    const float* __restrict__ x,
    const float* __restrict__ Wq, const float* __restrict__ bq,
    const float* __restrict__ Wk, const float* __restrict__ bk,
    const float* __restrict__ Wv, const float* __restrict__ bv,
    const float* __restrict__ pos,
    float* __restrict__ out)
{
    __shared__ _Float16 ekk_s[32 * PADJ];   // 33 KB
    __shared__ _Float16 ep_s [32 * PADJ];   // 33 KB
    __shared__ float    q_s  [32 * 16];     // 2 KB

    const int tid  = threadIdx.x;
    const int lane = tid & 63;
    const int wave = tid >> 6;
    const int l15  = lane & 15;
    const int quad = lane >> 4;

    const int bi  = blockIdx.x;
    const int b   = bi >> 7;            // batch
    const int dt  = (bi >> 4) & 7;      // d-tile
    const int tt  = bi & 15;            // t-tile
    const int d0g = dt * 16;
    const int t0g = tt * 32;

    const float* xb = x + b * SEQ * DIM;

    // ---- phase 1a: ep tile (all 256 threads; thread = (t, 64-j chunk)) ----
    {
        const int t  = tid >> 3;            // 0..31
        const int j0 = (tid & 7) * 64;
        const float* pr = pos + (t0g + t) * SEQ + j0;
        _Float16* dst = ep_s + t * PADJ + j0;
#pragma unroll
        for (int u = 0; u < 64; u += 8) {
            const float4 a = *(const float4*)(pr + u);
            const float4 c = *(const float4*)(pr + u + 4);
            half8 h;
            h[0] = (_Float16)__expf(a.x); h[1] = (_Float16)__expf(a.y);
            h[2] = (_Float16)__expf(a.z); h[3] = (_Float16)__expf(a.w);
            h[4] = (_Float16)__expf(c.x); h[5] = (_Float16)__expf(c.y);
            h[6] = (_Float16)__expf(c.z); h[7] = (_Float16)__expf(c.w);
            *(half8*)(dst + u) = h;
        }
    }

    // ---- phase 1b: k/v projection for this block's 16 d-cols, all 512 toks ----
    {
        half8 wkf[4], wvf[4];
        const float* wkr = Wk + (d0g + l15) * DIM + quad * 8;
        const float* wvr = Wv + (d0g + l15) * DIM + quad * 8;
#pragma unroll
        for (int ks = 0; ks < 4; ++ks) {
            wkf[ks] = ld8h(wkr + ks * 32);
            wvf[ks] = ld8h(wvr + ks * 32);
        }
        const float bkv = bk[d0g + l15];
        const float bvv = bv[d0g + l15];
        const int tokbase = wave * 128;

#pragma unroll
        for (int mt = 0; mt < 8; ++mt) {
            f32x4 ak = {0.f, 0.f, 0.f, 0.f};
            f32x4 av = {0.f, 0.f, 0.f, 0.f};
            const float* xr = xb + (tokbase + mt * 16 + l15) * DIM + quad * 8;
#pragma unroll
            for (int ks = 0; ks < 4; ++ks) {
                const half8 a = ld8h(xr + ks * 32);
                ak = __builtin_amdgcn_mfma_f32_16x16x32_f16(a, wkf[ks], ak, 0, 0, 0);
                av = __builtin_amdgcn_mfma_f32_16x16x32_f16(a, wvf[ks], av, 0, 0, 0);
            }
            // C layout: row(token) = quad*4 + r, col = l15
            const int j0r = tokbase + mt * 16 + quad * 4;
            half4 eh, evh;
#pragma unroll
            for (int r = 0; r < 4; ++r) {
                const float e = __expf(ak[r] + bkv);
                eh[r]  = (_Float16)e;
                evh[r] = (_Float16)(e * (av[r] + bvv));
            }
            *(half4*)(ekk_s + (2 * l15 + 0) * PADJ + j0r) = eh;
            *(half4*)(ekk_s + (2 * l15 + 1) * PADJ + j0r) = evh;
        }
    }

    // ---- phase 1c: q projection for (t0g..t0g+32) x (d0g..d0g+16), waves 0,1 ----
    if (wave < 2) {
        half8 wqf[4];
        const float* wqr = Wq + (d0g + l15) * DIM + quad * 8;
#pragma unroll
        for (int ks = 0; ks < 4; ++ks) wqf[ks] = ld8h(wqr + ks * 32);
        const float bqv = bq[d0g + l15];
        f32x4 aq = {0.f, 0.f, 0.f, 0.f};
        const float* xr = xb + (t0g + wave * 16 + l15) * DIM + quad * 8;
#pragma unroll
        for (int ks = 0; ks < 4; ++ks) {
            const half8 a = ld8h(xr + ks * 32);
            aq = __builtin_amdgcn_mfma_f32_16x16x32_f16(a, wqf[ks], aq, 0, 0, 0);
        }
#pragma unroll
        for (int r = 0; r < 4; ++r)
            q_s[(wave * 16 + quad * 4 + r) * 16 + l15] =
                1.f / (1.f + __expf(-(aq[r] + bqv)));
    }

    __syncthreads();

    // ---- phase 2: AFT GEMM from LDS ----
    const int wm  = wave & 1;
    const int wt  = wave >> 1;
    const int m0w = wm * 16;
    const int t0w = wt * 16;

    const _Float16* arow = ekk_s + (m0w + l15) * PADJ + quad * 8;
    const _Float16* brow = ep_s  + (t0w + l15) * PADJ + quad * 8;

    f32x4 acc0 = {0.f, 0.f, 0.f, 0.f};
    f32x4 acc1 = {0.f, 0.f, 0.f, 0.f};
#pragma unroll
    for (int ks = 0; ks < 16; ks += 2) {   // two interleaved chains for ILP
        const half8 a0 = *(const half8*)(arow + ks * 32);
        const half8 b0 = *(const half8*)(brow + ks * 32);
        const half8 a1 = *(const half8*)(arow + ks * 32 + 32);
        const half8 b1 = *(const half8*)(brow + ks * 32 + 32);
        acc0 = __builtin_amdgcn_mfma_f32_16x16x32_f16(a0, b0, acc0, 0, 0, 0);
        acc1 = __builtin_amdgcn_mfma_f32_16x16x32_f16(a1, b1, acc1, 0, 0, 0);
    }
    const f32x4 acc = acc0 + acc1;

    // lane holds rows m0w+quad*4+{0..3} = (den,num) for d-pair (dl, dl+1)
    const int dl = (m0w + quad * 4) >> 1;     // even, 0..14
    const int t  = t0w + l15;
    const float2 qv = { q_s[t * 16 + dl], q_s[t * 16 + dl + 1] };
    float2 o;
    o.x = qv.x * acc[1] / acc[0];
    o.y = qv.y * acc[3] / acc[2];
    *(float2*)(out + (b * SEQ + t0g + t) * DIM + d0g + dl) = o;
}

// ---------------------------------------------------------------------------
extern "C" void kernel_launch(void* const* d_in, const int* in_sizes, int n_in,
                              void* d_out, int out_size, void* d_ws, size_t ws_size,
                              hipStream_t stream) {
    const float* x   = (const float*)d_in[0];
    const float* Wq  = (const float*)d_in[1];
    const float* bq  = (const float*)d_in[2];
    const float* Wk  = (const float*)d_in[3];
    const float* bk  = (const float*)d_in[4];
    const float* Wv  = (const float*)d_in[5];
    const float* bv  = (const float*)d_in[6];
    const float* pos = (const float*)d_in[7];

    k_fused<<<512, 256, 0, stream>>>(x, Wq, bq, Wk, bk, Wv, bv, pos, (float*)d_out);
}

// Round 5
// 79.741 us; speedup vs baseline: 1.2131x; 1.2131x over previous
//
#include <hip/hip_runtime.h>

#define BATCH 4
#define SEQ   512
#define DIM   128

typedef _Float16 half8 __attribute__((ext_vector_type(8)));
typedef _Float16 half4 __attribute__((ext_vector_type(4)));
typedef float    f32x4 __attribute__((ext_vector_type(4)));

// ---------------------------------------------------------------------------
// K0 prep: f32 -> f16 conversions.
//   blocks [0,128)   : x      (262144)          -> x_h
//   blocks [128,256) : pos    (262144), exp()   -> ep_h
//   blocks [256,280) : Wq/Wk/Wv (16384 each)    -> wq_h/wk_h/wv_h
// ---------------------------------------------------------------------------
__global__ __launch_bounds__(256) void k_prep(
    const float* __restrict__ x, const float* __restrict__ pos,
    const float* __restrict__ Wq, const float* __restrict__ Wk,
    const float* __restrict__ Wv,
    _Float16* __restrict__ x_h, _Float16* __restrict__ ep_h,
    _Float16* __restrict__ wq_h, _Float16* __restrict__ wk_h,
    _Float16* __restrict__ wv_h)
{
    const int blk = blockIdx.x;
    const int tid = threadIdx.x;
    if (blk < 128) {
        const int i = (blk * 256 + tid) * 8;
        const float4 p0 = *(const float4*)(x + i);
        const float4 p1 = *(const float4*)(x + i + 4);
        half8 h;
        h[0]=(_Float16)p0.x; h[1]=(_Float16)p0.y; h[2]=(_Float16)p0.z; h[3]=(_Float16)p0.w;
        h[4]=(_Float16)p1.x; h[5]=(_Float16)p1.y; h[6]=(_Float16)p1.z; h[7]=(_Float16)p1.w;
        *(half8*)(x_h + i) = h;
    } else if (blk < 256) {
        const int i = ((blk - 128) * 256 + tid) * 8;
        const float4 p0 = *(const float4*)(pos + i);
        const float4 p1 = *(const float4*)(pos + i + 4);
        half8 h;
        h[0]=(_Float16)__expf(p0.x); h[1]=(_Float16)__expf(p0.y);
        h[2]=(_Float16)__expf(p0.z); h[3]=(_Float16)__expf(p0.w);
        h[4]=(_Float16)__expf(p1.x); h[5]=(_Float16)__expf(p1.y);
        h[6]=(_Float16)__expf(p1.z); h[7]=(_Float16)__expf(p1.w);
        *(half8*)(ep_h + i) = h;
    } else {
        const int r = blk - 256;                  // 0..23
        const float* src = (r < 8) ? Wq : ((r < 16) ? Wk : Wv);
        _Float16* dst    = (r < 8) ? wq_h : ((r < 16) ? wk_h : wv_h);
        const int i = ((r & 7) * 256 + tid) * 8;
        const float4 p0 = *(const float4*)(src + i);
        const float4 p1 = *(const float4*)(src + i + 4);
        half8 h;
        h[0]=(_Float16)p0.x; h[1]=(_Float16)p0.y; h[2]=(_Float16)p0.z; h[3]=(_Float16)p0.w;
        h[4]=(_Float16)p1.x; h[5]=(_Float16)p1.y; h[6]=(_Float16)p1.z; h[7]=(_Float16)p1.w;
        *(half8*)(dst + i) = h;
    }
}

// ---------------------------------------------------------------------------
// K1 proj (MFMA): D[token][col] = x @ W^T for q,k,v simultaneously.
// Wave tile 16m(token) x 16n(col); block = 4 waves stacked in m.
// Grid = 32 x 8 = 256 blocks.
// Epilogue:
//   q[b][tok][col]            = sigmoid(dq + bq)   (f32, natural layout)
//   ekk[b][2c+0][tok] (f16)   = exp(dk + bk)              (den operand)
//   ekk[b][2c+1][tok] (f16)   = exp(dk + bk)*(dv + bv)    (num operand)
// ---------------------------------------------------------------------------
__global__ __launch_bounds__(256) void k_proj(
    const _Float16* __restrict__ x_h,
    const _Float16* __restrict__ wq_h, const float* __restrict__ bq,
    const _Float16* __restrict__ wk_h, const float* __restrict__ bk,
    const _Float16* __restrict__ wv_h, const float* __restrict__ bv,
    float* __restrict__ qout, _Float16* __restrict__ ekk)
{
    const int tid  = threadIdx.x;
    const int lane = tid & 63;
    const int wave = tid >> 6;
    const int l15  = lane & 15;
    const int quad = lane >> 4;

    const int n0 = (blockIdx.x & 7) * 16;               // col tile
    const int m0 = (blockIdx.x >> 3) * 64 + wave * 16;  // token-row tile

    const _Float16* xa = x_h  + (m0 + l15) * DIM + quad * 8;
    const _Float16* wq = wq_h + (n0 + l15) * DIM + quad * 8;
    const _Float16* wk = wk_h + (n0 + l15) * DIM + quad * 8;
    const _Float16* wv = wv_h + (n0 + l15) * DIM + quad * 8;

    f32x4 aq = {0.f, 0.f, 0.f, 0.f};
    f32x4 ak = {0.f, 0.f, 0.f, 0.f};
    f32x4 av = {0.f, 0.f, 0.f, 0.f};

#pragma unroll
    for (int ks = 0; ks < 4; ++ks) {            // K = 128, 32 per step
        const half8 a  = *(const half8*)(xa + ks * 32);
        const half8 b0 = *(const half8*)(wq + ks * 32);
        const half8 b1 = *(const half8*)(wk + ks * 32);
        const half8 b2 = *(const half8*)(wv + ks * 32);
        aq = __builtin_amdgcn_mfma_f32_16x16x32_f16(a, b0, aq, 0, 0, 0);
        ak = __builtin_amdgcn_mfma_f32_16x16x32_f16(a, b1, ak, 0, 0, 0);
        av = __builtin_amdgcn_mfma_f32_16x16x32_f16(a, b2, av, 0, 0, 0);
    }

    const int c   = n0 + l15;
    const float bqv = bq[c];
    const float bkv = bk[c];
    const float bvv = bv[c];

    const int mrow = m0 + quad * 4;   // first of 4 token rows this lane holds
    const int b    = mrow >> 9;       // /512 (all 4 rows same batch)
    const int tok  = mrow & 511;

    half4 eh, evh;
#pragma unroll
    for (int r = 0; r < 4; ++r) {
        const float e  = __expf(ak[r] + bkv);
        const float vv = av[r] + bvv;
        const float qv = 1.f / (1.f + __expf(-(aq[r] + bqv)));
        eh[r]  = (_Float16)e;
        evh[r] = (_Float16)(e * vv);
        qout[(b * SEQ + tok + r) * DIM + c] = qv;
    }
    *(half4*)(ekk + ((b * 256) + 2 * c + 0) * SEQ + tok) = eh;
    *(half4*)(ekk + ((b * 256) + 2 * c + 1) * SEQ + tok) = evh;
}

// ---------------------------------------------------------------------------
// K2 AFT (MFMA, zero LDS): per b, D[m][t] = sum_j ekk[m][j] * ep[t][j]
//   m in [0,256): even rows = den (ek), odd rows = num (ekv).
// Wave tile 16m x 32t (2 MFMAs/k-step); block = 4 waves (2m x 2t) = 32m x 64t.
// Grid = 256 blocks; operands are direct 16B global loads (L2-resident).
// Epilogue: out[b][t][d] = q[b][t][d] * num/den.
// ---------------------------------------------------------------------------
__global__ __launch_bounds__(256) void k_aft(
    const _Float16* __restrict__ ekk,
    const _Float16* __restrict__ ep_h,
    const float* __restrict__ qout,
    float* __restrict__ out)
{
    const int tid  = threadIdx.x;
    const int lane = tid & 63;
    const int wave = tid >> 6;
    const int l15  = lane & 15;
    const int quad = lane >> 4;
    const int wm   = wave & 1;
    const int wn   = wave >> 1;

    const int b  = blockIdx.x >> 6;
    const int m0 = (((blockIdx.x >> 3) & 7) * 32) + wm * 16;  // [0,256)
    const int t0 = ((blockIdx.x & 7) * 64) + wn * 32;         // [0,512)

    const _Float16* arow  = ekk  + ((b * 256) + m0 + l15) * SEQ + quad * 8;
    const _Float16* brow0 = ep_h + (t0 + l15) * SEQ + quad * 8;
    const _Float16* brow1 = brow0 + 16 * SEQ;

    f32x4 acc0 = {0.f, 0.f, 0.f, 0.f};
    f32x4 acc1 = {0.f, 0.f, 0.f, 0.f};

#pragma unroll
    for (int ks = 0; ks < 16; ++ks) {           // K = 512, 32 per step
        const half8 a  = *(const half8*)(arow  + ks * 32);
        const half8 b0 = *(const half8*)(brow0 + ks * 32);
        const half8 b1 = *(const half8*)(brow1 + ks * 32);
        acc0 = __builtin_amdgcn_mfma_f32_16x16x32_f16(a, b0, acc0, 0, 0, 0);
        acc1 = __builtin_amdgcn_mfma_f32_16x16x32_f16(a, b1, acc1, 0, 0, 0);
    }

    // lane holds rows m0+quad*4+{0..3} = (den,num) for d0 and d0+1
    const int d0 = (m0 + quad * 4) >> 1;   // even
#pragma unroll
    for (int i = 0; i < 2; ++i) {
        const f32x4 acc = i ? acc1 : acc0;
        const int t = t0 + i * 16 + l15;
        const float2 qv = *(const float2*)(qout + ((b * SEQ) + t) * DIM + d0);
        float2 o;
        o.x = qv.x * acc[1] / acc[0];
        o.y = qv.y * acc[3] / acc[2];
        *(float2*)(out + ((b * SEQ) + t) * DIM + d0) = o;
    }
}

// ---------------------------------------------------------------------------
extern "C" void kernel_launch(void* const* d_in, const int* in_sizes, int n_in,
                              void* d_out, int out_size, void* d_ws, size_t ws_size,
                              hipStream_t stream) {
    const float* x   = (const float*)d_in[0];
    const float* Wq  = (const float*)d_in[1];
    const float* bq  = (const float*)d_in[2];
    const float* Wk  = (const float*)d_in[3];
    const float* bk  = (const float*)d_in[4];
    const float* Wv  = (const float*)d_in[5];
    const float* bv  = (const float*)d_in[6];
    const float* pos = (const float*)d_in[7];

    float* outp = (float*)d_out;
    char*  ws   = (char*)d_ws;

    _Float16* x_h  = (_Float16*)(ws);                       // 512 KB
    _Float16* ep_h = (_Float16*)(ws + (512 << 10));         // 512 KB
    _Float16* ekk  = (_Float16*)(ws + (1024 << 10));        // 1 MB
    _Float16* wq_h = (_Float16*)(ws + (2048 << 10));        // 32 KB
    _Float16* wk_h = (_Float16*)(ws + (2080 << 10));        // 32 KB
    _Float16* wv_h = (_Float16*)(ws + (2112 << 10));        // 32 KB
    float*    qout = (float*)   (ws + (2144 << 10));        // 1 MB

    k_prep<<<280, 256, 0, stream>>>(x, pos, Wq, Wk, Wv, x_h, ep_h, wq_h, wk_h, wv_h);
    k_proj<<<256, 256, 0, stream>>>(x_h, wq_h, bq, wk_h, bk, wv_h, bv, qout, ekk);
    k_aft<<<256, 256, 0, stream>>>(ekk, ep_h, qout, outp);
}